// Round 1
// baseline (15256.285 us; speedup 1.0000x reference)
//
#include <hip/hip_runtime.h>
#include <hip/hip_bf16.h>
#include <cstdint>
#include <cstddef>

// ============================================================================
// BiSLSTM (B=32, S=1024, E=256, H=256, K=2), fp32 in/out.  Round 3.
//
// R2 was cross-block-latency bound: TWO device-scope exchange round trips
// (h then s[idx]) serialized on every timestep's dependence cycle.
// R3 removes the second exchange: each block REPLICATES the s[idx] recurrence
// locally.  Full 32x256 r[idx] = sigm(x@Wrx[idx] + h@Wrh[idx] + br) via a
// per-block MFMA GEMM with Wrh[idx] resident in VGPRs (32 frags/thread); the
// only per-step exchange is {h_t bf16, c_t f32, rsx[idx]_t bf16} with ONE
// flag per block.  Replicated arithmetic is bit-identical across blocks
// (same bf16/f32 inputs, same op order) so staged s-fragments stay globally
// consistent.  Barriers/step 8 -> 4; payload stored directly by producing
// threads (single ack before the flag); x_{t+1} prefetch + x@Wx z-partial
// MFMAs overlap the poll/gather window.
// ============================================================================

typedef __bf16 bf16x8 __attribute__((ext_vector_type(8)));
typedef float  f32x4  __attribute__((ext_vector_type(4)));
typedef unsigned long long u64x2 __attribute__((ext_vector_type(2)));

#define DEVINL __device__ __forceinline__

constexpr int Ss = 1024;

// ---- ws layout (bytes) ----
constexpr size_t OFF_FLAGS = 0;                   // 1 KB, zeroed by prepass
constexpr size_t OFF_H   = 1024;                  // [2 pc][2 d][32 b][256 u] bf16
constexpr size_t SZ_HS   = (size_t)2*2*32*512;    // 65536
constexpr size_t OFF_R   = OFF_H + SZ_HS;         // [2 pc][2 d][256 j][32 b] bf16
constexpr size_t OFF_WH  = OFF_R + SZ_HS;         // [2][1024 col][256 k] bf16
constexpr size_t SZ_W    = (size_t)2*1024*256*2;  // 1 MB
constexpr size_t OFF_WX  = OFF_WH + SZ_W;
constexpr size_t OFF_WS  = OFF_WX + SZ_W;
constexpr size_t OFF_WRX = OFF_WS + SZ_W;         // [2][2*256 j][256 k] bf16
constexpr size_t SZ_WR   = (size_t)2*2*256*256*2; // 512 KB
constexpr size_t OFF_WRH = OFF_WRX + SZ_WR;
constexpr size_t OFF_C   = OFF_WRH + SZ_WR;       // [2 pc][2 d][256 j][32 b] f32 (128 KB)

DEVINL unsigned short f2bf(float f) {                 // RNE fp32->bf16
    unsigned u = __builtin_bit_cast(unsigned, f);
    u += 0x7FFFu + ((u >> 16) & 1u);
    return (unsigned short)(u >> 16);
}
DEVINL unsigned long long pack4(float4 v) {
    return (unsigned long long)f2bf(v.x) | ((unsigned long long)f2bf(v.y) << 16)
         | ((unsigned long long)f2bf(v.z) << 32) | ((unsigned long long)f2bf(v.w) << 48);
}
DEVINL float sigm(float x) { return 1.f / (1.f + __expf(-x)); }

// ---------------------------------------------------------------------------
__global__ void prepass(const float* __restrict__ Wx0, const float* __restrict__ Wh0,
                        const float* __restrict__ Ws0,
                        const float* __restrict__ Wx1, const float* __restrict__ Wh1,
                        const float* __restrict__ Ws1,
                        const float* __restrict__ Wrx0, const float* __restrict__ Wrh0,
                        const float* __restrict__ Wrx1, const float* __restrict__ Wrh1,
                        unsigned char* __restrict__ ws)
{
    unsigned short* whT  = (unsigned short*)(ws + OFF_WH);
    unsigned short* wxT  = (unsigned short*)(ws + OFF_WX);
    unsigned short* wsT  = (unsigned short*)(ws + OFF_WS);
    unsigned short* wrxT = (unsigned short*)(ws + OFF_WRX);
    unsigned short* wrhT = (unsigned short*)(ws + OFF_WRH);
    int tid = blockIdx.x * blockDim.x + threadIdx.x;
    int NT  = gridDim.x * blockDim.x;
    // [d][n][k] = W[k*1024+n]
    for (int e = tid; e < 2*1024*256; e += NT) {
        int d = e >> 18, r = e & 262143, n = r >> 8, k = r & 255;
        whT[e] = f2bf((d ? Wh1 : Wh0)[k*1024 + n]);
        wxT[e] = f2bf((d ? Wx1 : Wx0)[k*1024 + n]);
        wsT[e] = f2bf((d ? Ws1 : Ws0)[k*1024 + n]);
    }
    // [d][kk*256+j][k] = W[(kk*256+k)*256+j]
    for (int e = tid; e < 2*2*256*256; e += NT) {
        int d = e >> 17, r = e & 131071, kk = r >> 16, r2 = r & 65535;
        int j = r2 >> 8, k = r2 & 255;
        wrxT[e] = f2bf((d ? Wrx1 : Wrx0)[(kk*256 + k)*256 + j]);
        wrhT[e] = f2bf((d ? Wrh1 : Wrh0)[(kk*256 + k)*256 + j]);
    }
    // zero flags (ws poisoned each launch)
    if (blockIdx.x == 0 && threadIdx.x < 256) ((unsigned*)ws)[threadIdx.x] = 0u;
}

// ---------------------------------------------------------------------------
// sA fragment layout: [2 Mt][16 kt][4 lq][16 m] x 16B.  kt 0..7 = h, 8..15 = s.
#define FRAG_PTR(Mt,kt,lqv,m) \
    ((unsigned long long*)(sA + (size_t)(((((Mt)*16+(kt))*4+(lqv))*16+(m))*8)))

__launch_bounds__(256, 1)
__global__ void bislstm(const float* __restrict__ inputs, const float* __restrict__ mask,
                        const float* __restrict__ b0,  const float* __restrict__ b1,
                        const float* __restrict__ br0, const float* __restrict__ br1,
                        const int* __restrict__ idxp,
                        unsigned char* __restrict__ ws, float* __restrict__ out)
{
    const int bid = blockIdx.x;
    const int d   = bid >> 5;          // direction
    const int g   = bid & 31;          // unit group (units 8g..8g+7)
    const int tid = threadIdx.x;
    const int wave = tid >> 6, lane = tid & 63;
    const int lm = lane & 15, lq = lane >> 4;

    __shared__ __align__(16) unsigned short sA[16384];   // 32 KB frag-order A (h,s)
    __shared__ float zs[2][32][16];
    __shared__ float rsxS[2][32][16];                    // parity dbuf, both shares, own cols
    __shared__ float rshS[32][16];
    __shared__ float mL[32];

    const unsigned short* whT  = (const unsigned short*)(ws + OFF_WH)  + (size_t)d*1024*256;
    const unsigned short* wxT  = (const unsigned short*)(ws + OFF_WX)  + (size_t)d*1024*256;
    const unsigned short* wsT  = (const unsigned short*)(ws + OFF_WS)  + (size_t)d*1024*256;
    const unsigned short* wrxT = (const unsigned short*)(ws + OFF_WRX) + (size_t)d*2*256*256;
    const unsigned short* wrhT = (const unsigned short*)(ws + OFF_WRH) + (size_t)d*2*256*256;
    unsigned long long* Hbuf  = (unsigned long long*)(ws + OFF_H);
    unsigned short*     HbufS = (unsigned short*)(ws + OFF_H);
    unsigned long long* Rbuf  = (unsigned long long*)(ws + OFF_R);
    float*              CbufF = (float*)(ws + OFF_C);
    unsigned* flags = (unsigned*)ws + d*64;
    const int idxv = idxp[0];
    const float* bd  = d ? b1  : b0;
    const float* brd = d ? br1 : br0;

    // z roles (unchanged from R2)
    const int zMt = wave & 1, zNt = wave >> 1;
    const int znl = zNt*16 + lm;
    const int zcol = (znl >> 3)*256 + g*8 + (znl & 7);
    const int rks = lm >> 3;
    const int rj  = g*8 + (lm & 7);

    // ---- preload weight B-fragments ----
    // waves 0,1: rwf = Wrh (small rsh for output share), waves 2,3: rwf = Wrx (rsx)
    bf16x8 whf[8], wsf[8], wxf[8], rwf[8], wbig[4][8];
#pragma unroll
    for (int kt = 0; kt < 8; ++kt) {
        whf[kt] = *(const bf16x8*)(whT + (size_t)zcol*256 + kt*32 + lq*8);
        wsf[kt] = *(const bf16x8*)(wsT + (size_t)zcol*256 + kt*32 + lq*8);
        wxf[kt] = *(const bf16x8*)(wxT + (size_t)zcol*256 + kt*32 + lq*8);
    }
    {
        const unsigned short* wrT = (wave < 2) ? wrhT : wrxT;
#pragma unroll
        for (int kt = 0; kt < 8; ++kt)
            rwf[kt] = *(const bf16x8*)(wrT + (size_t)(rks*256 + rj)*256 + kt*32 + lq*8);
    }
    // full Wrh[idx]: wave w owns cols j = w*64 + n*16 + lm, n = 0..3
    float brB[4]; bool ownN[4];
#pragma unroll
    for (int n = 0; n < 4; ++n) {
        const int j16 = wave*64 + n*16 + lm;
#pragma unroll
        for (int kt = 0; kt < 8; ++kt)
            wbig[n][kt] = *(const bf16x8*)(wrhT + (size_t)(idxv*256 + j16)*256 + kt*32 + lq*8);
        brB[n]  = brd[idxv*256 + j16];
        ownN[n] = ((j16 >> 3) == g);
    }

    // ---- zero sA (h_{-1}=0, s_{-1}=0) ----
    {
        unsigned long long* z8 = (unsigned long long*)sA;
#pragma unroll
        for (int i = 0; i < 16; ++i) z8[tid + 256*i] = 0ULL;
    }

    // ---- prologue: x_0 frags -> zacc (x@Wx partial) + rsx_0 (waves>=2) ----
    f32x4 zacc;
    {
        const int tx0 = d ? (Ss - 1) : 0;
        const float* xp = inputs + (((size_t)(zMt*16 + lm)*Ss + tx0) << 8) + lq*8;
        bf16x8 xf[8];
#pragma unroll
        for (int kt = 0; kt < 8; ++kt) {
            float4 v0 = *(const float4*)(xp + kt*32);
            float4 v1 = *(const float4*)(xp + kt*32 + 4);
            u64x2 pk; pk.x = pack4(v0); pk.y = pack4(v1);
            xf[kt] = __builtin_bit_cast(bf16x8, pk);
        }
        f32x4 a = {0.f, 0.f, 0.f, 0.f};
#pragma unroll
        for (int kt = 0; kt < 8; ++kt)
            a = __builtin_amdgcn_mfma_f32_16x16x32_bf16(xf[kt], wxf[kt], a, 0, 0, 0);
        zacc = a;
        if (wave >= 2) {
            f32x4 ra = {0.f, 0.f, 0.f, 0.f};
#pragma unroll
            for (int kt = 0; kt < 8; ++kt)
                ra = __builtin_amdgcn_mfma_f32_16x16x32_bf16(xf[kt], rwf[kt], ra, 0, 0, 0);
#pragma unroll
            for (int r = 0; r < 4; ++r) rsxS[0][zMt*16 + lq*4 + r][lm] = ra[r];
            if (rks == idxv) {
                float4 f4; f4.x = ra[0]; f4.y = ra[1]; f4.z = ra[2]; f4.w = ra[3];
                __hip_atomic_store(Rbuf + (size_t)d*2048 + ((rj*32 + zMt*16 + lq*4) >> 2),
                                   pack4(f4), __ATOMIC_RELAXED, __HIP_MEMORY_SCOPE_AGENT);
            }
        }
    }
    __syncthreads();

    // per-thread elementwise cell constants + state (registers, same thread every step)
    const int eb = tid >> 3, ej = tid & 7;
    const int gj = g*8 + ej;
    const float bias_i = bd[gj], bias_f = bd[256+gj], bias_g = bd[512+gj], bias_o = bd[768+gj];
    const float brr0 = brd[gj], brr1 = brd[256+gj];
    float hprev = 0.f, cprev = 0.f, s1prev = 0.f;
    float sreg[2][4][4] = {};                     // replicated s[idx] state (this wave's tiles)
    unsigned long long cg[2][4][2], rg[2][4];     // gathered c (f32x4) / rsx (bf16x4) per tile-row

    const unsigned short* aBase = sA + (size_t)(zMt*8192 + lq*128 + lm*8);

#pragma unroll 1
    for (int t = 0; t < Ss; ++t) {
        const int tx = d ? (Ss - 1 - t) : t;
        const int pc = t & 1, pcn = pc ^ 1;
        const unsigned want = (unsigned)(t + 1);
        const bool more = (t + 1 < Ss);

        // ---- P1: z = (x@Wx partial) + h@Wh + s@Ws ----
        if (tid < 32) mL[tid] = mask[(size_t)tid*Ss + tx];
        {
            f32x4 acc = zacc;
#pragma unroll
            for (int kt = 0; kt < 8; ++kt)
                acc = __builtin_amdgcn_mfma_f32_16x16x32_bf16(*(const bf16x8*)(aBase + kt*512), whf[kt], acc, 0, 0, 0);
#pragma unroll
            for (int kt = 0; kt < 8; ++kt)
                acc = __builtin_amdgcn_mfma_f32_16x16x32_bf16(*(const bf16x8*)(aBase + (8+kt)*512), wsf[kt], acc, 0, 0, 0);
#pragma unroll
            for (int r = 0; r < 4; ++r)
                zs[zNt][zMt*16 + lq*4 + r][lm] = acc[r];
        }
        __syncthreads();                                   // S1

        // ---- P2: gates -> c,h ; direct payload stores (h bf16, c f32) ----
        float m_, cu_, hu_;
        {
            float zi = zs[0][eb][ej]   + bias_i;
            float zf = zs[0][eb][8+ej] + bias_f;
            float zg = zs[1][eb][ej]   + bias_g;
            float zo = zs[1][eb][8+ej] + bias_o;
            float cn = sigm(zf)*cprev + sigm(zi)*tanhf(zg);
            float hn = sigm(zo)*tanhf(cn);
            m_  = mL[eb];
            cu_ = m_*cn + (1.f - m_)*cprev;
            hu_ = m_*hn + (1.f - m_)*hprev;
            cprev = cu_; hprev = hu_;
            __hip_atomic_store(HbufS + (size_t)(pc*2 + d)*8192 + (size_t)eb*256 + gj,
                               f2bf(hu_), __ATOMIC_RELAXED, __HIP_MEMORY_SCOPE_AGENT);
            __hip_atomic_store(CbufF + (size_t)(pc*2 + d)*8192 + (size_t)gj*32 + eb,
                               cu_, __ATOMIC_RELAXED, __HIP_MEMORY_SCOPE_AGENT);
        }
        asm volatile("s_waitcnt vmcnt(0)" ::: "memory");   // payload ack'd (+Rbuf/rsx from P3 of t-1)
        __syncthreads();                                   // S2

        // ---- P3: flag ; x' prefetch ; poll ; gather ; overlapped MFMA ----
        if (tid == 0)
            __hip_atomic_store(flags + g, want, __ATOMIC_RELAXED, __HIP_MEMORY_SCOPE_AGENT);
        out[((size_t)tx*32 + eb)*512 + d*256 + gj] = hu_;
        out[16777216 + ((size_t)tx*32 + eb)*512 + d*256 + gj] = cu_;

        bf16x8 xf[8];
        if (more) {
            const int txn = d ? (Ss - 2 - t) : (t + 1);
            const float* xp = inputs + (((size_t)(zMt*16 + lm)*Ss + txn) << 8) + lq*8;
#pragma unroll
            for (int kt = 0; kt < 8; ++kt) {
                float4 v0 = *(const float4*)(xp + kt*32);
                float4 v1 = *(const float4*)(xp + kt*32 + 4);
                u64x2 pk; pk.x = pack4(v0); pk.y = pack4(v1);
                xf[kt] = __builtin_bit_cast(bf16x8, pk);
            }
        }
        for (;;) {
            unsigned v = __hip_atomic_load(flags + (lane & 31), __ATOMIC_RELAXED, __HIP_MEMORY_SCOPE_AGENT);
            if (__ballot(v < want) == 0ULL) break;
            __builtin_amdgcn_s_sleep(1);
        }
        asm volatile("" ::: "memory");
        // gather h_t -> frag region kt 0..7
        {
            const unsigned long long* src = Hbuf + (size_t)(pc*2 + d)*2048;
#pragma unroll
            for (int i = 0; i < 4; ++i) {
                int b_ = (tid & 7) + 8*i;
                int jj = tid >> 3;
                unsigned long long v0 = __hip_atomic_load(src + (size_t)b_*64 + jj*2,     __ATOMIC_RELAXED, __HIP_MEMORY_SCOPE_AGENT);
                unsigned long long v1 = __hip_atomic_load(src + (size_t)b_*64 + jj*2 + 1, __ATOMIC_RELAXED, __HIP_MEMORY_SCOPE_AGENT);
                u64x2 pk; pk.x = v0; pk.y = v1;
                *(u64x2*)FRAG_PTR(b_ >> 4, jj >> 2, jj & 3, b_ & 15) = pk;
            }
        }
        // gather c_t (f32) and rsx[idx]_t (bf16) straight into the consuming lanes
        {
            const unsigned long long* Cb = (const unsigned long long*)(ws + OFF_C) + (size_t)(pc*2 + d)*4096;
            const unsigned long long* Rb = (const unsigned long long*)(ws + OFF_R) + (size_t)(pc*2 + d)*2048;
#pragma unroll
            for (int Mt = 0; Mt < 2; ++Mt)
#pragma unroll
            for (int n = 0; n < 4; ++n) {
                const int j16 = wave*64 + n*16 + lm;
                const int b0  = Mt*16 + lq*4;
                cg[Mt][n][0] = __hip_atomic_load(Cb + ((j16*32 + b0) >> 1),     __ATOMIC_RELAXED, __HIP_MEMORY_SCOPE_AGENT);
                cg[Mt][n][1] = __hip_atomic_load(Cb + ((j16*32 + b0) >> 1) + 1, __ATOMIC_RELAXED, __HIP_MEMORY_SCOPE_AGENT);
                rg[Mt][n]    = __hip_atomic_load(Rb + ((j16*32 + b0) >> 2),     __ATOMIC_RELAXED, __HIP_MEMORY_SCOPE_AGENT);
            }
        }
        if (more) {
            // next-step z x-part (pure-reg MFMA overlaps gather latency)
            f32x4 a = {0.f, 0.f, 0.f, 0.f};
#pragma unroll
            for (int kt = 0; kt < 8; ++kt)
                a = __builtin_amdgcn_mfma_f32_16x16x32_bf16(xf[kt], wxf[kt], a, 0, 0, 0);
            zacc = a;
            if (wave >= 2) {       // rsx for step t+1: own 16 cols (both shares)
                f32x4 ra = {0.f, 0.f, 0.f, 0.f};
#pragma unroll
                for (int kt = 0; kt < 8; ++kt)
                    ra = __builtin_amdgcn_mfma_f32_16x16x32_bf16(xf[kt], rwf[kt], ra, 0, 0, 0);
#pragma unroll
                for (int r = 0; r < 4; ++r) rsxS[pcn][zMt*16 + lq*4 + r][lm] = ra[r];
                if (rks == idxv) {
                    float4 f4; f4.x = ra[0]; f4.y = ra[1]; f4.z = ra[2]; f4.w = ra[3];
                    __hip_atomic_store(Rbuf + (size_t)(pcn*2 + d)*2048 + ((rj*32 + zMt*16 + lq*4) >> 2),
                                       pack4(f4), __ATOMIC_RELAXED, __HIP_MEMORY_SCOPE_AGENT);
                }
            }
        }
        __syncthreads();                                   // S3

        // ---- P4: replicated r[idx] GEMM + s[idx] update + s-frag writes ----
#pragma unroll
        for (int Mt = 0; Mt < 2; ++Mt) {
            bf16x8 hf[8];
#pragma unroll
            for (int kt = 0; kt < 8; ++kt)
                hf[kt] = *(const bf16x8*)(sA + (size_t)(Mt*8192 + kt*512 + lq*128 + lm*8));
            float mrow[4];
#pragma unroll
            for (int r = 0; r < 4; ++r) mrow[r] = mL[Mt*16 + lq*4 + r];
#pragma unroll
            for (int n = 0; n < 4; ++n) {
                f32x4 a = {0.f, 0.f, 0.f, 0.f};
#pragma unroll
                for (int kt = 0; kt < 8; ++kt)
                    a = __builtin_amdgcn_mfma_f32_16x16x32_bf16(hf[kt], wbig[n][kt], a, 0, 0, 0);
                const int j16 = wave*64 + n*16 + lm;
                const int kts = 8 + wave*2 + (n >> 1);
                const int lqs = (n*2 + (lm >> 3)) & 3;
#pragma unroll
                for (int r = 0; r < 4; ++r) {
                    const int b = Mt*16 + lq*4 + r;
                    float cv = __builtin_bit_cast(float, (unsigned)(cg[Mt][n][r >> 1] >> ((r & 1)*32)));
                    float rx = __builtin_bit_cast(float, ((unsigned)(unsigned short)(rg[Mt][n] >> (r*16))) << 16);
                    float rr = sigm(a[r] + rx + brB[n]);
                    float so = sreg[Mt][n][r];
                    float sn = rr*so + (1.f - rr)*cv;
                    float su = mrow[r]*sn + (1.f - mrow[r])*so;
                    sreg[Mt][n][r] = su;
                    sA[(size_t)(Mt*8192 + kts*512 + lqs*128 + (b & 15)*8 + (lm & 7))] = f2bf(su);
                    if (ownN[n])
                        out[33554432 + (((size_t)idxv*1024 + tx)*32 + b)*512 + d*256 + j16] = su;
                }
            }
            if (wave < 2 && Mt == zMt) {   // small rsh (h@Wrh, own 16 cols) reusing hf
                f32x4 ra = {0.f, 0.f, 0.f, 0.f};
#pragma unroll
                for (int kt = 0; kt < 8; ++kt)
                    ra = __builtin_amdgcn_mfma_f32_16x16x32_bf16(hf[kt], rwf[kt], ra, 0, 0, 0);
#pragma unroll
                for (int r = 0; r < 4; ++r) rshS[zMt*16 + lq*4 + r][lm] = ra[r];
            }
        }
        __syncthreads();                                   // S4

        // ---- P5: output-only share (1-idx), owner units, fp32-local ----
        {
            const int k1 = 1 - idxv;
            float rv = rsxS[pc][eb][k1*8 + ej] + rshS[eb][k1*8 + ej] + (k1 ? brr1 : brr0);
            float rr = sigm(rv);
            float sn = rr*s1prev + (1.f - rr)*cu_;
            float su = m_*sn + (1.f - m_)*s1prev;
            s1prev = su;
            out[33554432 + (((size_t)k1*1024 + tx)*32 + eb)*512 + d*256 + gj] = su;
        }
        // no barrier needed: next conflicting writes are behind S1/S3 of t+1
    }
}

// ---------------------------------------------------------------------------
extern "C" void kernel_launch(void* const* d_in, const int* in_sizes, int n_in,
                              void* d_out, int out_size, void* d_ws, size_t ws_size,
                              hipStream_t stream) {
    const float* inputs = (const float*)d_in[0];
    const float* mask_  = (const float*)d_in[1];
    const float* Wx0  = (const float*)d_in[2];
    const float* Wh0  = (const float*)d_in[3];
    const float* Ws0  = (const float*)d_in[4];
    const float* b0   = (const float*)d_in[5];
    const float* Wrx0 = (const float*)d_in[6];
    const float* Wrh0 = (const float*)d_in[7];
    const float* br0  = (const float*)d_in[8];
    const float* Wx1  = (const float*)d_in[9];
    const float* Wh1  = (const float*)d_in[10];
    const float* Ws1  = (const float*)d_in[11];
    const float* b1   = (const float*)d_in[12];
    const float* Wrx1 = (const float*)d_in[13];
    const float* Wrh1 = (const float*)d_in[14];
    const float* br1  = (const float*)d_in[15];
    const int*   idxp = (const int*)d_in[16];
    unsigned char* ws = (unsigned char*)d_ws;

    hipLaunchKernelGGL(prepass, dim3(512), dim3(256), 0, stream,
                       Wx0, Wh0, Ws0, Wx1, Wh1, Ws1, Wrx0, Wrh0, Wrx1, Wrh1, ws);
    hipLaunchKernelGGL(bislstm, dim3(64), dim3(256), 0, stream,
                       inputs, mask_, b0, b1, br0, br1, idxp,
                       ws, (float*)d_out);
}